// Round 5
// baseline (9297.995 us; speedup 1.0000x reference)
//
#include <hip/hip_runtime.h>

#define DEV static __device__ __forceinline__

// LayerNorm over 3 elements: (x-m)/sqrt(v+eps)*g + b
DEV void ln3(float& a, float& b, float& c, const float* g, const float* bt) {
  float m = (a + b + c) * (1.0f / 3.0f);
  float d0 = a - m, d1 = b - m, d2 = c - m;
  float v = (d0 * d0 + d1 * d1 + d2 * d2) * (1.0f / 3.0f);
  float rs = rsqrtf(v + 1e-5f);
  a = fmaf(d0 * rs, g[0], bt[0]);
  b = fmaf(d1 * rs, g[1], bt[1]);
  c = fmaf(d2 * rs, g[2], bt[2]);
}

// ---------------------------------------------------------------------------
// Prepack fp32 weights into ws:
//   FS[l][j][8] = {w1[j][0..2], b1[j], w2[0][j], w2[1][j], w2[2][j], 0}
//   SMALL[l][128]: attn/LN scalars | GLOB[16]: enc_norm g,b ; dec_norm g,b
// ---------------------------------------------------------------------------
__global__ void __launch_bounds__(256) prepack_kernel(
    const float* ea_w, const float* ea_b, const float* ea_ow, const float* ea_ob,
    const float* el1g, const float* el1b, const float* el2g, const float* el2b,
    const float* ef1w, const float* ef1b, const float* ef2w, const float* ef2b,
    const float* eng, const float* enb,
    const float* dsw, const float* dsb, const float* dsow, const float* dsob,
    const float* dcw, const float* dcb, const float* dcow, const float* dcob,
    const float* dl1g, const float* dl1b, const float* dl2g, const float* dl2b,
    const float* dl3g, const float* dl3b,
    const float* df1w, const float* df1b, const float* df2w, const float* df2b,
    const float* dng, const float* dnb,
    float* ws) {
  const int l = blockIdx.x, tid = threadIdx.x;
  const bool enc = l < 12;
  const int li = enc ? l : l - 12;
  const float* f1w = (enc ? ef1w : df1w) + li * 2048 * 3;
  const float* f1b = (enc ? ef1b : df1b) + li * 2048;
  const float* f2w = (enc ? ef2w : df2w) + li * 3 * 2048;
  float* FS = ws + (size_t)l * 16384;
  for (int j = tid; j < 2048; j += 256) {
    FS[j * 8 + 0] = f1w[j * 3 + 0];
    FS[j * 8 + 1] = f1w[j * 3 + 1];
    FS[j * 8 + 2] = f1w[j * 3 + 2];
    FS[j * 8 + 3] = f1b[j];
    FS[j * 8 + 4] = f2w[j];
    FS[j * 8 + 5] = f2w[2048 + j];
    FS[j * 8 + 6] = f2w[4096 + j];
    FS[j * 8 + 7] = 0.0f;
  }
  float* S = ws + 24 * 16384 + l * 128;
  if (tid == 0) {
    // 0-26 qkv W | 27-35 qkv b | 36-44 ow | 45-47 ob | 48-53 ln1 g,b
    // 54-59 ln2 g,b | 60-62 ffn b2
    const float* aw = (enc ? ea_w : dsw) + li * 27;
    const float* ab = (enc ? ea_b : dsb) + li * 9;
    const float* aow = (enc ? ea_ow : dsow) + li * 9;
    const float* aob = (enc ? ea_ob : dsob) + li * 3;
    for (int i = 0; i < 27; ++i) S[i] = aw[i];
    for (int i = 0; i < 9; ++i) S[27 + i] = ab[i];
    for (int i = 0; i < 9; ++i) S[36 + i] = aow[i];
    for (int i = 0; i < 3; ++i) S[45 + i] = aob[i];
    const float* p;
    p = (enc ? el1g : dl1g) + li * 3; for (int i = 0; i < 3; ++i) S[48 + i] = p[i];
    p = (enc ? el1b : dl1b) + li * 3; for (int i = 0; i < 3; ++i) S[51 + i] = p[i];
    p = (enc ? el2g : dl2g) + li * 3; for (int i = 0; i < 3; ++i) S[54 + i] = p[i];
    p = (enc ? el2b : dl2b) + li * 3; for (int i = 0; i < 3; ++i) S[57 + i] = p[i];
    p = (enc ? ef2b : df2b) + li * 3; for (int i = 0; i < 3; ++i) S[60 + i] = p[i];
    if (!enc) {
      // 64-72 cross qW | 73-75 cross qb | 76-84 cross ow | 85-87 cross ob
      // 88-93 ln3 g,b | 94-102 cross kW | 103-105 kb | 106-114 vW | 115-117 vb
      const float* cw = dcw + li * 27;
      for (int i = 0; i < 9; ++i) {
        S[64 + i] = cw[i];
        S[94 + i] = cw[9 + i];
        S[106 + i] = cw[18 + i];
      }
      const float* cb = dcb + li * 9;
      for (int i = 0; i < 3; ++i) {
        S[73 + i] = cb[i];
        S[103 + i] = cb[3 + i];
        S[115 + i] = cb[6 + i];
      }
      for (int i = 0; i < 9; ++i) S[76 + i] = dcow[li * 9 + i];
      for (int i = 0; i < 3; ++i) S[85 + i] = dcob[li * 3 + i];
      p = dl3g + li * 3; for (int i = 0; i < 3; ++i) S[88 + i] = p[i];
      p = dl3b + li * 3; for (int i = 0; i < 3; ++i) S[91 + i] = p[i];
    }
  }
  if (l == 0 && tid == 1) {
    float* G = ws + 24 * 16384 + 24 * 128;
    for (int i = 0; i < 3; ++i) {
      G[i] = eng[i]; G[3 + i] = enb[i];
      G[6 + i] = dng[i]; G[9 + i] = dnb[i];
    }
  }
}

// ---------------------------------------------------------------------------
// One transformer layer. Phases (dec): P1 qkv | P2 self-partials |
// P3 redundant-C1 + cross-partials | P4 redundant-C2 + FFN + final LN.
// Encoder (ckv==null): P1 | P2 | P4(redundant-C1 + FFN).
// All phases are multi-wave; 4 (dec) / 3 (enc) barriers per layer.
// R rows; row R-1 is the zero-representative with key-mult (64-t) when t>0.
// ---------------------------------------------------------------------------
DEV void run_layer(const float* sm, const float* fs, const float (*ckv)[8],
                   float (*h)[4], float (*hln)[4], float* kvq,
                   float (*p1)[28], float (*p2)[28],
                   float (*o_s)[4], const float* glob,
                   int R, int t, bool from_os, bool wpred,
                   int wave, int lane, int tid) {
  // ---- P1: QKV, thread (r,o) computes one projection output ----
  {
    const int r = tid >> 4, o = tid & 15;
    if (r < R && o < 10) {
      float x0, x1, x2;
      if (from_os) {
        const bool real = r < t;  // rows >= t are the zero rep
        x0 = real ? o_s[r][0] : 0.f;
        x1 = real ? o_s[r][1] : 0.f;
        x2 = real ? o_s[r][2] : 0.f;
      } else {
        x0 = h[r][0]; x1 = h[r][1]; x2 = h[r][2];
      }
      if (o < 9) {
        // layout per row (stride 13): q0 q1 q2 _ k0 k1 k2 mult v0 v1 v2
        float v = fmaf(sm[o * 3], x0,
                  fmaf(sm[o * 3 + 1], x1, fmaf(sm[o * 3 + 2], x2, sm[27 + o])));
        kvq[r * 13 + o + o / 3] = v;
      } else {  // o == 9: key multiplicity; publish x into h for layer-0
        kvq[r * 13 + 7] = (ckv && r == R - 1 && t > 0) ? (float)(64 - t) : 1.0f;
        if (from_os) {  // FIX: residual stream must see this step's inputs
          h[r][0] = x0; h[r][1] = x1; h[r][2] = x2;
        }
      }
    }
  }
  __syncthreads();
  // ---- P2: self-attn partial softmax sums; wave = hd + 3*chunk ----
  if (wave < 12 && lane < R) {
    const int hd = wave % 3, c = wave / 3;
    const int p0 = c * 16;
    float q = kvq[lane * 13 + hd] * 1.44269504f;
    float den = 0.f, num = 0.f;
    if (p0 < R) {
#pragma unroll
      for (int pp = 0; pp < 16; ++pp) {
        const int p = p0 + pp;
        const int pc = min(p, R - 1);
        float e = exp2f(q * kvq[pc * 13 + 4 + hd]) * kvq[pc * 13 + 7];
        e = (p < R) ? e : 0.f;
        den += e;
        num = fmaf(e, kvq[pc * 13 + 8 + hd], num);
      }
    }
    p1[lane][2 * wave] = den;
    p1[lane][2 * wave + 1] = num;
  }
  __syncthreads();
  if (ckv) {
    // ---- P3: redundant C1 per lane-row + cross-q + cross partials ----
    if (wave < 12 && lane < R) {
      const int r = lane, hd = wave % 3, c = wave / 3;
      float d0 = p1[r][0] + p1[r][6] + p1[r][12] + p1[r][18];
      float n0 = p1[r][1] + p1[r][7] + p1[r][13] + p1[r][19];
      float d1 = p1[r][2] + p1[r][8] + p1[r][14] + p1[r][20];
      float n1 = p1[r][3] + p1[r][9] + p1[r][15] + p1[r][21];
      float d2 = p1[r][4] + p1[r][10] + p1[r][16] + p1[r][22];
      float n2 = p1[r][5] + p1[r][11] + p1[r][17] + p1[r][23];
      float oh0 = __fdividef(n0, d0), oh1 = __fdividef(n1, d1), oh2 = __fdividef(n2, d2);
      float a0 = fmaf(sm[36], oh0, fmaf(sm[37], oh1, fmaf(sm[38], oh2, sm[45]))) + h[r][0];
      float a1 = fmaf(sm[39], oh0, fmaf(sm[40], oh1, fmaf(sm[41], oh2, sm[46]))) + h[r][1];
      float a2 = fmaf(sm[42], oh0, fmaf(sm[43], oh1, fmaf(sm[44], oh2, sm[47]))) + h[r][2];
      ln3(a0, a1, a2, sm + 48, sm + 51);
      if (wave == 0) { hln[r][0] = a0; hln[r][1] = a1; hln[r][2] = a2; }
      float q = fmaf(sm[64 + hd * 3], a0,
                fmaf(sm[64 + hd * 3 + 1], a1,
                fmaf(sm[64 + hd * 3 + 2], a2, sm[73 + hd]))) * 1.44269504f;
      const int p0 = c * 16;
      float den = 0.f, num = 0.f;
#pragma unroll
      for (int pp = 0; pp < 16; ++pp) {
        const int p = p0 + pp;
        float e = exp2f(q * ckv[p][hd]);
        den += e;
        num = fmaf(e, ckv[p][3 + hd], num);
      }
      p2[r][2 * wave] = den;
      p2[r][2 * wave + 1] = num;
    }
    __syncthreads();
  }
  // ---- P4: redundant C-combine per own row + FFN + final LN ----
  {
    const int nw = (R + 3) >> 2;  // contiguous rows 4w..4w+3
    if (wave < nw) {
      const float(*pp)[28] = ckv ? p2 : p1;
      const float* ow = ckv ? sm + 76 : sm + 36;
      const float* ob = ckv ? sm + 85 : sm + 45;
      const float* lg = ckv ? sm + 54 : sm + 48;
      const float* lb = ckv ? sm + 57 : sm + 51;
      float X0[4], X1[4], X2[4];
#pragma unroll
      for (int i = 0; i < 4; ++i) {
        const int rc = min(wave * 4 + i, R - 1);
        float d0 = pp[rc][0] + pp[rc][6] + pp[rc][12] + pp[rc][18];
        float n0 = pp[rc][1] + pp[rc][7] + pp[rc][13] + pp[rc][19];
        float d1 = pp[rc][2] + pp[rc][8] + pp[rc][14] + pp[rc][20];
        float n1 = pp[rc][3] + pp[rc][9] + pp[rc][15] + pp[rc][21];
        float d2 = pp[rc][4] + pp[rc][10] + pp[rc][16] + pp[rc][22];
        float n2 = pp[rc][5] + pp[rc][11] + pp[rc][17] + pp[rc][23];
        float oh0 = __fdividef(n0, d0), oh1 = __fdividef(n1, d1), oh2 = __fdividef(n2, d2);
        float hr0, hr1, hr2;
        if (ckv) { hr0 = hln[rc][0]; hr1 = hln[rc][1]; hr2 = hln[rc][2]; }
        else     { hr0 = h[rc][0];   hr1 = h[rc][1];   hr2 = h[rc][2]; }
        float a0 = fmaf(ow[0], oh0, fmaf(ow[1], oh1, fmaf(ow[2], oh2, ob[0]))) + hr0;
        float a1 = fmaf(ow[3], oh0, fmaf(ow[4], oh1, fmaf(ow[5], oh2, ob[1]))) + hr1;
        float a2 = fmaf(ow[6], oh0, fmaf(ow[7], oh1, fmaf(ow[8], oh2, ob[2]))) + hr2;
        ln3(a0, a1, a2, lg, lb);
        X0[i] = a0; X1[i] = a1; X2[i] = a2;
      }
      // FFN: lanes split 2048 hidden units; weights from L2 (interleaved 32B/j)
      float A0[4] = {0, 0, 0, 0}, A1[4] = {0, 0, 0, 0}, A2[4] = {0, 0, 0, 0};
      const float4* FS4 = (const float4*)fs;
#pragma unroll 4
      for (int kk = 0; kk < 32; ++kk) {
        const int j = lane + (kk << 6);
        float4 a = FS4[2 * j];
        float4 c = FS4[2 * j + 1];
#pragma unroll
        for (int i = 0; i < 4; ++i) {
          float tt = fmaf(a.x, X0[i], fmaf(a.y, X1[i], fmaf(a.z, X2[i], a.w)));
          tt = fmaxf(tt, 0.0f);
          A0[i] = fmaf(c.x, tt, A0[i]);
          A1[i] = fmaf(c.y, tt, A1[i]);
          A2[i] = fmaf(c.z, tt, A2[i]);
        }
      }
#pragma unroll
      for (int m = 1; m < 64; m <<= 1) {
#pragma unroll
        for (int i = 0; i < 4; ++i) {
          A0[i] += __shfl_xor(A0[i], m, 64);
          A1[i] += __shfl_xor(A1[i], m, 64);
          A2[i] += __shfl_xor(A2[i], m, 64);
        }
      }
      if (lane == 0) {
        const float* fg = ckv ? sm + 88 : sm + 54;
        const float* fb = ckv ? sm + 91 : sm + 57;
#pragma unroll
        for (int i = 0; i < 4; ++i) {
          const int r = wave * 4 + i;
          if (r < R) {
            float y0 = A0[i] + sm[60] + X0[i];
            float y1 = A1[i] + sm[61] + X1[i];
            float y2 = A2[i] + sm[62] + X2[i];
            ln3(y0, y1, y2, fg, fb);
            h[r][0] = y0; h[r][1] = y1; h[r][2] = y2;
            if (wpred && r == R - 1) {  // pred[t] = dec_norm(final zero-rep row)
              ln3(y0, y1, y2, glob + 6, glob + 9);
              o_s[t][0] = y0; o_s[t][1] = y1; o_s[t][2] = y2;
            }
          }
        }
      }
    }
    __syncthreads();
  }
}

// ---------------------------------------------------------------------------
// Main kernel: one block per batch element. Encoder -> cross K/V precompute
// -> 63 autoregressive decode steps with zero-row dedup -> output transpose.
// ---------------------------------------------------------------------------
__global__ void __launch_bounds__(1024) tf_kernel(const float* src, const float* angle,
                                                  const float* ws, float* out) {
  __shared__ float small_s[24][128];
  __shared__ float glob[16];
  __shared__ __align__(16) float h[64][4];
  __shared__ __align__(16) float hln[64][4];
  __shared__ float kvq[64 * 13];
  __shared__ __align__(16) float part1[64][28];
  __shared__ __align__(16) float part2[64][28];
  __shared__ __align__(16) float o_s[64][4];
  __shared__ float ckcv[12][64][8];
  const int b = blockIdx.x;
  const int tid = threadIdx.x, wave = tid >> 6, lane = tid & 63;
  const float* FS = ws;
  const float* SM = ws + 24 * 16384;
  const float* GB = SM + 24 * 128;
  for (int i = tid; i < 24 * 128; i += 1024) ((float*)small_s)[i] = SM[i];
  if (tid < 16) glob[tid] = GB[tid];
  if (tid < 64) {
    float x0 = src[b * 128 + tid];
    float x1 = src[b * 128 + 64 + tid];
    float x2 = angle[b];
    h[tid][0] = x0; h[tid][1] = x1; h[tid][2] = x2;
    // o_s[0] = input row 0 (decode seed); rest zero
    o_s[tid][0] = (tid == 0) ? x0 : 0.f;
    o_s[tid][1] = (tid == 0) ? x1 : 0.f;
    o_s[tid][2] = (tid == 0) ? x2 : 0.f;
  }
  __syncthreads();
  // ---- encoder ----
  for (int l = 0; l < 12; ++l)
    run_layer(small_s[l], FS + (size_t)l * 16384, (const float(*)[8]) nullptr,
              h, hln, kvq, part1, part2, o_s, glob, 64, 0, false, false,
              wave, lane, tid);
  // final encoder LN -> mem (in place in h)
  if (tid < 64) {
    float a = h[tid][0], bb = h[tid][1], c = h[tid][2];
    ln3(a, bb, c, glob + 0, glob + 3);
    h[tid][0] = a; h[tid][1] = bb; h[tid][2] = c;
  }
  __syncthreads();
  // ---- precompute cross-attn K/V per decoder layer ----
  if (wave < 12) {
    const float* sm = small_s[12 + wave];
    float m0 = h[lane][0], m1 = h[lane][1], m2 = h[lane][2];
    float k0 = fmaf(sm[94], m0, fmaf(sm[95], m1, fmaf(sm[96], m2, sm[103])));
    float k1 = fmaf(sm[97], m0, fmaf(sm[98], m1, fmaf(sm[99], m2, sm[104])));
    float k2 = fmaf(sm[100], m0, fmaf(sm[101], m1, fmaf(sm[102], m2, sm[105])));
    float v0 = fmaf(sm[106], m0, fmaf(sm[107], m1, fmaf(sm[108], m2, sm[115])));
    float v1 = fmaf(sm[109], m0, fmaf(sm[110], m1, fmaf(sm[111], m2, sm[116])));
    float v2 = fmaf(sm[112], m0, fmaf(sm[113], m1, fmaf(sm[114], m2, sm[117])));
    ckcv[wave][lane][0] = k0; ckcv[wave][lane][1] = k1; ckcv[wave][lane][2] = k2;
    ckcv[wave][lane][3] = v0; ckcv[wave][lane][4] = v1; ckcv[wave][lane][5] = v2;
  }
  __syncthreads();
  // ---- autoregressive decode: step t fills o_s[t] ----
  for (int t = 1; t < 64; ++t) {
    const int R = t + 1;
    for (int l = 0; l < 12; ++l)
      run_layer(small_s[12 + l], FS + (size_t)(12 + l) * 16384, ckcv[l],
                h, hln, kvq, part1, part2, o_s, glob, R, t,
                /*from_os=*/l == 0, /*wpred=*/l == 11, wave, lane, tid);
  }
  // ---- output: [B,3,T] ----
  if (tid < 192) {
    int d = tid / 64, tt = tid % 64;
    out[b * 192 + tid] = o_s[tt][d];
  }
}

extern "C" void kernel_launch(void* const* d_in, const int* in_sizes, int n_in,
                              void* d_out, int out_size, void* d_ws, size_t ws_size,
                              hipStream_t stream) {
  (void)in_sizes; (void)n_in; (void)out_size; (void)ws_size;
  float* ws = (float*)d_ws;
  prepack_kernel<<<24, 256, 0, stream>>>(
      (const float*)d_in[2], (const float*)d_in[3], (const float*)d_in[4], (const float*)d_in[5],
      (const float*)d_in[6], (const float*)d_in[7], (const float*)d_in[8], (const float*)d_in[9],
      (const float*)d_in[10], (const float*)d_in[11], (const float*)d_in[12], (const float*)d_in[13],
      (const float*)d_in[14], (const float*)d_in[15],
      (const float*)d_in[16], (const float*)d_in[17], (const float*)d_in[18], (const float*)d_in[19],
      (const float*)d_in[20], (const float*)d_in[21], (const float*)d_in[22], (const float*)d_in[23],
      (const float*)d_in[24], (const float*)d_in[25], (const float*)d_in[26], (const float*)d_in[27],
      (const float*)d_in[28], (const float*)d_in[29],
      (const float*)d_in[30], (const float*)d_in[31], (const float*)d_in[32], (const float*)d_in[33],
      (const float*)d_in[34], (const float*)d_in[35],
      ws);
  tf_kernel<<<32, 1024, 0, stream>>>((const float*)d_in[0], (const float*)d_in[1], ws,
                                     (float*)d_out);
}

// Round 6
// 6352.880 us; speedup vs baseline: 1.4636x; 1.4636x over previous
//
#include <hip/hip_runtime.h>

#define DEV static __device__ __forceinline__

typedef _Float16 h2 __attribute__((ext_vector_type(2)));

DEV float fdot2f(h2 a, h2 b, float c) {
#if __has_builtin(__builtin_amdgcn_fdot2)
  return __builtin_amdgcn_fdot2(a, b, c, false);
#else
  return c + (float)a.x * (float)b.x + (float)a.y * (float)b.y;
#endif
}

// LayerNorm over 3 elements: (x-m)/sqrt(v+eps)*g + b
DEV void ln3(float& a, float& b, float& c, const float* g, const float* bt) {
  float m = (a + b + c) * (1.0f / 3.0f);
  float d0 = a - m, d1 = b - m, d2 = c - m;
  float v = (d0 * d0 + d1 * d1 + d2 * d2) * (1.0f / 3.0f);
  float rs = rsqrtf(v + 1e-5f);
  a = fmaf(d0 * rs, g[0], bt[0]);
  b = fmaf(d1 * rs, g[1], bt[1]);
  c = fmaf(d2 * rs, g[2], bt[2]);
}

DEV unsigned pkh2(float a, float b) {
  h2 v = {(_Float16)a, (_Float16)b};
  return __builtin_bit_cast(unsigned, v);
}

// ---------------------------------------------------------------------------
// Prepack:
//  FA[l][jp] = uint4{ pk(w1[2jp][d],w1[2jp+1][d]) d=0..2, pk(b1 pair) }
//  FB[l][jp] = uint4{ pk(w2[d][2jp],w2[d][2jp+1]) d=0..2, 0 }
//  SM[l][128] fp32 attn/LN scalars | GLOB[16]
//  float offsets: FA = 0, FB = 24*4096, SM = 196608, GLOB = SM + 24*128
// ---------------------------------------------------------------------------
__global__ void __launch_bounds__(256) prepack_kernel(
    const float* ea_w, const float* ea_b, const float* ea_ow, const float* ea_ob,
    const float* el1g, const float* el1b, const float* el2g, const float* el2b,
    const float* ef1w, const float* ef1b, const float* ef2w, const float* ef2b,
    const float* eng, const float* enb,
    const float* dsw, const float* dsb, const float* dsow, const float* dsob,
    const float* dcw, const float* dcb, const float* dcow, const float* dcob,
    const float* dl1g, const float* dl1b, const float* dl2g, const float* dl2b,
    const float* dl3g, const float* dl3b,
    const float* df1w, const float* df1b, const float* df2w, const float* df2b,
    const float* dng, const float* dnb,
    float* ws) {
  const int l = blockIdx.x, tid = threadIdx.x;
  const bool enc = l < 12;
  const int li = enc ? l : l - 12;
  const float* f1w = (enc ? ef1w : df1w) + li * 2048 * 3;
  const float* f1b = (enc ? ef1b : df1b) + li * 2048;
  const float* f2w = (enc ? ef2w : df2w) + li * 3 * 2048;
  uint4* FA4 = (uint4*)ws + (size_t)l * 1024;
  uint4* FB4 = (uint4*)ws + 24 * 1024 + (size_t)l * 1024;
  for (int jp = tid; jp < 1024; jp += 256) {
    const int j0 = jp * 2, j1 = j0 + 1;
    uint4 A;
    A.x = pkh2(f1w[j0 * 3 + 0], f1w[j1 * 3 + 0]);
    A.y = pkh2(f1w[j0 * 3 + 1], f1w[j1 * 3 + 1]);
    A.z = pkh2(f1w[j0 * 3 + 2], f1w[j1 * 3 + 2]);
    A.w = pkh2(f1b[j0], f1b[j1]);
    FA4[jp] = A;
    uint4 Bv;
    Bv.x = pkh2(f2w[j0], f2w[j1]);
    Bv.y = pkh2(f2w[2048 + j0], f2w[2048 + j1]);
    Bv.z = pkh2(f2w[4096 + j0], f2w[4096 + j1]);
    Bv.w = 0u;
    FB4[jp] = Bv;
  }
  float* S = ws + 196608 + l * 128;
  if (tid == 0) {
    // 0-26 qkv W | 27-35 qkv b | 36-44 ow | 45-47 ob | 48-53 ln1 g,b
    // 54-59 ln2 g,b | 60-62 ffn b2
    const float* aw = (enc ? ea_w : dsw) + li * 27;
    const float* ab = (enc ? ea_b : dsb) + li * 9;
    const float* aow = (enc ? ea_ow : dsow) + li * 9;
    const float* aob = (enc ? ea_ob : dsob) + li * 3;
    for (int i = 0; i < 27; ++i) S[i] = aw[i];
    for (int i = 0; i < 9; ++i) S[27 + i] = ab[i];
    for (int i = 0; i < 9; ++i) S[36 + i] = aow[i];
    for (int i = 0; i < 3; ++i) S[45 + i] = aob[i];
    const float* p;
    p = (enc ? el1g : dl1g) + li * 3; for (int i = 0; i < 3; ++i) S[48 + i] = p[i];
    p = (enc ? el1b : dl1b) + li * 3; for (int i = 0; i < 3; ++i) S[51 + i] = p[i];
    p = (enc ? el2g : dl2g) + li * 3; for (int i = 0; i < 3; ++i) S[54 + i] = p[i];
    p = (enc ? el2b : dl2b) + li * 3; for (int i = 0; i < 3; ++i) S[57 + i] = p[i];
    p = (enc ? ef2b : df2b) + li * 3; for (int i = 0; i < 3; ++i) S[60 + i] = p[i];
    if (!enc) {
      // 64-72 cross qW | 73-75 qb | 76-84 cross ow | 85-87 ob | 88-93 ln3 g,b
      // 94-102 kW | 103-105 kb | 106-114 vW | 115-117 vb
      const float* cw = dcw + li * 27;
      for (int i = 0; i < 9; ++i) {
        S[64 + i] = cw[i];
        S[94 + i] = cw[9 + i];
        S[106 + i] = cw[18 + i];
      }
      const float* cb = dcb + li * 9;
      for (int i = 0; i < 3; ++i) {
        S[73 + i] = cb[i];
        S[103 + i] = cb[3 + i];
        S[115 + i] = cb[6 + i];
      }
      for (int i = 0; i < 9; ++i) S[76 + i] = dcow[li * 9 + i];
      for (int i = 0; i < 3; ++i) S[85 + i] = dcob[li * 3 + i];
      p = dl3g + li * 3; for (int i = 0; i < 3; ++i) S[88 + i] = p[i];
      p = dl3b + li * 3; for (int i = 0; i < 3; ++i) S[91 + i] = p[i];
    }
  }
  if (l == 0 && tid == 1) {
    float* G = ws + 196608 + 24 * 128;
    for (int i = 0; i < 3; ++i) {
      G[i] = eng[i]; G[3 + i] = enb[i];
      G[6 + i] = dng[i]; G[9 + i] = dnb[i];
    }
  }
}

// Packed-f16 FFN for NR rows (rows = wave + 16*i). f32 accumulate via dot2.
template <int NR>
DEV void ffn_core(const uint4* FA, const uint4* FB,
                  const float (&X0)[4], const float (&X1)[4], const float (&X2)[4],
                  float (&acc)[4][3], int lane) {
  h2 xd0[NR], xd1[NR], xd2[NR];
#pragma unroll
  for (int i = 0; i < NR; ++i) {
    xd0[i] = h2{(_Float16)X0[i], (_Float16)X0[i]};
    xd1[i] = h2{(_Float16)X1[i], (_Float16)X1[i]};
    xd2[i] = h2{(_Float16)X2[i], (_Float16)X2[i]};
  }
#pragma unroll
  for (int i = 0; i < NR; ++i) { acc[i][0] = 0.f; acc[i][1] = 0.f; acc[i][2] = 0.f; }
  const h2 z = {(_Float16)0, (_Float16)0};
#pragma unroll 4
  for (int kk = 0; kk < 16; ++kk) {
    const int jp = lane + (kk << 6);
    uint4 a = FA[jp];
    uint4 c = FB[jp];
    h2 wa0 = __builtin_bit_cast(h2, a.x), wa1 = __builtin_bit_cast(h2, a.y);
    h2 wa2 = __builtin_bit_cast(h2, a.z), bb = __builtin_bit_cast(h2, a.w);
    h2 wc0 = __builtin_bit_cast(h2, c.x), wc1 = __builtin_bit_cast(h2, c.y);
    h2 wc2 = __builtin_bit_cast(h2, c.z);
#pragma unroll
    for (int i = 0; i < NR; ++i) {
      h2 t = wa0 * xd0[i] + wa1 * xd1[i] + wa2 * xd2[i] + bb;
      t = __builtin_elementwise_max(t, z);
      acc[i][0] = fdot2f(wc0, t, acc[i][0]);
      acc[i][1] = fdot2f(wc1, t, acc[i][1]);
      acc[i][2] = fdot2f(wc2, t, acc[i][2]);
    }
  }
#pragma unroll
  for (int m = 1; m < 64; m <<= 1) {
#pragma unroll
    for (int i = 0; i < NR; ++i) {
      acc[i][0] += __shfl_xor(acc[i][0], m, 64);
      acc[i][1] += __shfl_xor(acc[i][1], m, 64);
      acc[i][2] += __shfl_xor(acc[i][2], m, 64);
    }
  }
}

// ---------------------------------------------------------------------------
// One transformer layer. DEC: P1 qkv | P2 self-partials | P3 redundant-C1 +
// cross-partials | P4 combine + packed FFN + final LN. ENC: P1 | P2 | P4.
// kvq row stride 13: q0..2 [3] k0..2(4-6) mult(7) v0..2(8-10).
// Rows >= R have mult=0 (padding) so P2 runs full 16-key unrolled loops.
// ---------------------------------------------------------------------------
template <bool DEC>
DEV void run_layer(const float* sm, const uint4* FA, const uint4* FB,
                   const float (*ckv)[8],
                   float (*h)[5], float (*hln)[5], float* kvq,
                   float (*p1)[25], float (*p2)[25],
                   float (*o_s)[5], const float* glob,
                   int R, int t, bool from_os, bool wpred,
                   int wave, int lane, int tid) {
  // ---- P1: QKV; thread (r,o) computes one projection output ----
  {
    const int r = tid >> 4, o = tid & 15;
    if (r < R && o <= 9) {
      float x0, x1, x2;
      if (DEC && from_os) {
        const bool real = r < t;  // rows >= t are the zero rep
        x0 = real ? o_s[r][0] : 0.f;
        x1 = real ? o_s[r][1] : 0.f;
        x2 = real ? o_s[r][2] : 0.f;
      } else {
        x0 = h[r][0]; x1 = h[r][1]; x2 = h[r][2];
      }
      if (o < 9) {
        float v = fmaf(sm[o * 3], x0,
                  fmaf(sm[o * 3 + 1], x1, fmaf(sm[o * 3 + 2], x2, sm[27 + o])));
        kvq[r * 13 + o + o / 3] = v;
      } else {  // o == 9: key multiplicity; publish x into h for layer-0
        kvq[r * 13 + 7] = (DEC && r == R - 1 && t > 0) ? (float)(64 - t) : 1.0f;
        if (DEC && from_os) { h[r][0] = x0; h[r][1] = x1; h[r][2] = x2; }
      }
    }
    if (DEC && o == 9 && r >= R) kvq[r * 13 + 7] = 0.f;  // pad: dead keys
  }
  __syncthreads();
  // ---- P2: self-attn partials; wave = hd + 3*chunk; full 16-key unroll ----
  if (wave < 12) {
    const int hd = wave % 3, c = wave / 3;
    const int p0 = c * 16;
    float den = 0.f, num = 0.f;
    if (p0 < R) {
      const float q = kvq[lane * 13 + hd] * 1.44269504f;
#pragma unroll
      for (int pp = 0; pp < 16; ++pp) {
        const int p = p0 + pp;
        float e = exp2f(q * kvq[p * 13 + 4 + hd]);
        if (DEC) e *= kvq[p * 13 + 7];  // mult (0 for pad rows)
        den += e;
        num = fmaf(e, kvq[p * 13 + 8 + hd], num);
      }
    }
    p1[lane][2 * wave] = den;
    p1[lane][2 * wave + 1] = num;
  }
  __syncthreads();
  if (DEC) {
    // ---- P3: redundant C1 per lane-row + cross-q + cross partials ----
    if (wave < 12) {
      const int r = lane, hd = wave % 3, c = wave / 3;
      float d0 = p1[r][0] + p1[r][6] + p1[r][12] + p1[r][18];
      float n0 = p1[r][1] + p1[r][7] + p1[r][13] + p1[r][19];
      float d1 = p1[r][2] + p1[r][8] + p1[r][14] + p1[r][20];
      float n1 = p1[r][3] + p1[r][9] + p1[r][15] + p1[r][21];
      float d2 = p1[r][4] + p1[r][10] + p1[r][16] + p1[r][22];
      float n2 = p1[r][5] + p1[r][11] + p1[r][17] + p1[r][23];
      float oh0 = __fdividef(n0, d0), oh1 = __fdividef(n1, d1), oh2 = __fdividef(n2, d2);
      float a0 = fmaf(sm[36], oh0, fmaf(sm[37], oh1, fmaf(sm[38], oh2, sm[45]))) + h[r][0];
      float a1 = fmaf(sm[39], oh0, fmaf(sm[40], oh1, fmaf(sm[41], oh2, sm[46]))) + h[r][1];
      float a2 = fmaf(sm[42], oh0, fmaf(sm[43], oh1, fmaf(sm[44], oh2, sm[47]))) + h[r][2];
      ln3(a0, a1, a2, sm + 48, sm + 51);
      if (wave == 0 && r < R) { hln[r][0] = a0; hln[r][1] = a1; hln[r][2] = a2; }
      float q = fmaf(sm[64 + hd * 3], a0,
                fmaf(sm[64 + hd * 3 + 1], a1,
                fmaf(sm[64 + hd * 3 + 2], a2, sm[73 + hd]))) * 1.44269504f;
      const int p0 = c * 16;
      float den = 0.f, num = 0.f;
#pragma unroll
      for (int pp = 0; pp < 16; ++pp) {
        const int p = p0 + pp;
        float e = exp2f(q * ckv[p][hd]);
        den += e;
        num = fmaf(e, ckv[p][3 + hd], num);
      }
      p2[r][2 * wave] = den;
      p2[r][2 * wave + 1] = num;
    }
    __syncthreads();
  }
  // ---- P4: combine + packed FFN + final LN; rows = wave + 16*i ----
  {
    const int nr = (wave < R) ? (1 + (R - 1 - wave) / 16) : 0;
    if (nr > 0) {
      const float(*pp)[25] = DEC ? p2 : p1;
      const float* ow = DEC ? sm + 76 : sm + 36;
      const float* ob = DEC ? sm + 85 : sm + 45;
      const float* lg = DEC ? sm + 54 : sm + 48;
      const float* lb = DEC ? sm + 57 : sm + 51;
      float X0[4], X1[4], X2[4];
#pragma unroll
      for (int i = 0; i < 4; ++i) {
        X0[i] = 0.f; X1[i] = 0.f; X2[i] = 0.f;
        if (i < nr) {
          const int rc = wave + 16 * i;
          float d0 = pp[rc][0] + pp[rc][6] + pp[rc][12] + pp[rc][18];
          float n0 = pp[rc][1] + pp[rc][7] + pp[rc][13] + pp[rc][19];
          float d1 = pp[rc][2] + pp[rc][8] + pp[rc][14] + pp[rc][20];
          float n1 = pp[rc][3] + pp[rc][9] + pp[rc][15] + pp[rc][21];
          float d2 = pp[rc][4] + pp[rc][10] + pp[rc][16] + pp[rc][22];
          float n2 = pp[rc][5] + pp[rc][11] + pp[rc][17] + pp[rc][23];
          float oh0 = __fdividef(n0, d0), oh1 = __fdividef(n1, d1), oh2 = __fdividef(n2, d2);
          float hr0, hr1, hr2;
          if (DEC) { hr0 = hln[rc][0]; hr1 = hln[rc][1]; hr2 = hln[rc][2]; }
          else     { hr0 = h[rc][0];   hr1 = h[rc][1];   hr2 = h[rc][2]; }
          float a0 = fmaf(ow[0], oh0, fmaf(ow[1], oh1, fmaf(ow[2], oh2, ob[0]))) + hr0;
          float a1 = fmaf(ow[3], oh0, fmaf(ow[4], oh1, fmaf(ow[5], oh2, ob[1]))) + hr1;
          float a2 = fmaf(ow[6], oh0, fmaf(ow[7], oh1, fmaf(ow[8], oh2, ob[2]))) + hr2;
          ln3(a0, a1, a2, lg, lb);
          X0[i] = a0; X1[i] = a1; X2[i] = a2;
        }
      }
      float acc[4][3];
      switch (nr) {
        case 1: ffn_core<1>(FA, FB, X0, X1, X2, acc, lane); break;
        case 2: ffn_core<2>(FA, FB, X0, X1, X2, acc, lane); break;
        case 3: ffn_core<3>(FA, FB, X0, X1, X2, acc, lane); break;
        default: ffn_core<4>(FA, FB, X0, X1, X2, acc, lane); break;
      }
      if (lane == 0) {
        const float* fg = DEC ? sm + 88 : sm + 54;
        const float* fb = DEC ? sm + 91 : sm + 57;
#pragma unroll
        for (int i = 0; i < 4; ++i) {
          if (i < nr) {
            const int r = wave + 16 * i;
            float y0 = acc[i][0] + sm[60] + X0[i];
            float y1 = acc[i][1] + sm[61] + X1[i];
            float y2 = acc[i][2] + sm[62] + X2[i];
            ln3(y0, y1, y2, fg, fb);
            h[r][0] = y0; h[r][1] = y1; h[r][2] = y2;
            if (DEC && wpred && r == R - 1) {  // pred[t] = dec_norm(zero-rep)
              ln3(y0, y1, y2, glob + 6, glob + 9);
              o_s[t][0] = y0; o_s[t][1] = y1; o_s[t][2] = y2;
            }
          }
        }
      }
    }
    __syncthreads();
  }
}

// ---------------------------------------------------------------------------
// Main kernel: one block per batch element. Encoder -> cross K/V precompute
// -> 63 autoregressive decode steps with zero-row dedup -> output transpose.
// ---------------------------------------------------------------------------
__global__ void __launch_bounds__(1024) tf_kernel(const float* src, const float* angle,
                                                  const float* ws, float* out) {
  __shared__ float small_s[24][128];
  __shared__ float glob[16];
  __shared__ float h[64][5];
  __shared__ float hln[64][5];
  __shared__ float kvq[64 * 13];
  __shared__ float part1[64][25];
  __shared__ float part2[64][25];
  __shared__ float o_s[64][5];
  __shared__ float ckcv[12][64][8];
  const int b = blockIdx.x;
  const int tid = threadIdx.x, wave = tid >> 6, lane = tid & 63;
  const uint4* FA = (const uint4*)ws;
  const uint4* FB = (const uint4*)ws + 24 * 1024;
  const float* SM = ws + 196608;
  const float* GB = SM + 24 * 128;
  for (int i = tid; i < 24 * 128; i += 1024) ((float*)small_s)[i] = SM[i];
  if (tid < 16) glob[tid] = GB[tid];
  if (tid < 64) {
    float x0 = src[b * 128 + tid];
    float x1 = src[b * 128 + 64 + tid];
    float x2 = angle[b];
    h[tid][0] = x0; h[tid][1] = x1; h[tid][2] = x2;
    o_s[tid][0] = (tid == 0) ? x0 : 0.f;
    o_s[tid][1] = (tid == 0) ? x1 : 0.f;
    o_s[tid][2] = (tid == 0) ? x2 : 0.f;
  }
  __syncthreads();
  // ---- encoder (R=64) ----
  for (int l = 0; l < 12; ++l)
    run_layer<false>(small_s[l], FA + (size_t)l * 1024, FB + (size_t)l * 1024,
                     nullptr, h, hln, kvq, part1, part2, o_s, glob,
                     64, 0, false, false, wave, lane, tid);
  // final encoder LN -> mem (in place in h)
  if (tid < 64) {
    float a = h[tid][0], bb = h[tid][1], c = h[tid][2];
    ln3(a, bb, c, glob + 0, glob + 3);
    h[tid][0] = a; h[tid][1] = bb; h[tid][2] = c;
  }
  __syncthreads();
  // ---- precompute cross-attn K/V per decoder layer ----
  if (wave < 12) {
    const float* sm = small_s[12 + wave];
    float m0 = h[lane][0], m1 = h[lane][1], m2 = h[lane][2];
    float k0 = fmaf(sm[94], m0, fmaf(sm[95], m1, fmaf(sm[96], m2, sm[103])));
    float k1 = fmaf(sm[97], m0, fmaf(sm[98], m1, fmaf(sm[99], m2, sm[104])));
    float k2 = fmaf(sm[100], m0, fmaf(sm[101], m1, fmaf(sm[102], m2, sm[105])));
    float v0 = fmaf(sm[106], m0, fmaf(sm[107], m1, fmaf(sm[108], m2, sm[115])));
    float v1 = fmaf(sm[109], m0, fmaf(sm[110], m1, fmaf(sm[111], m2, sm[116])));
    float v2 = fmaf(sm[112], m0, fmaf(sm[113], m1, fmaf(sm[114], m2, sm[117])));
    ckcv[wave][lane][0] = k0; ckcv[wave][lane][1] = k1; ckcv[wave][lane][2] = k2;
    ckcv[wave][lane][3] = v0; ckcv[wave][lane][4] = v1; ckcv[wave][lane][5] = v2;
  }
  __syncthreads();
  // ---- autoregressive decode: step t fills o_s[t] ----
  for (int t = 1; t < 64; ++t) {
    const int R = t + 1;
    for (int l = 0; l < 12; ++l)
      run_layer<true>(small_s[12 + l], FA + (size_t)(12 + l) * 1024,
                      FB + (size_t)(12 + l) * 1024, ckcv[l],
                      h, hln, kvq, part1, part2, o_s, glob, R, t,
                      /*from_os=*/l == 0, /*wpred=*/l == 11, wave, lane, tid);
  }
  // ---- output: [B,3,T] ----
  if (tid < 192) {
    int d = tid / 64, tt = tid % 64;
    out[b * 192 + tid] = o_s[tt][d];
  }
}

extern "C" void kernel_launch(void* const* d_in, const int* in_sizes, int n_in,
                              void* d_out, int out_size, void* d_ws, size_t ws_size,
                              hipStream_t stream) {
  (void)in_sizes; (void)n_in; (void)out_size; (void)ws_size;
  float* ws = (float*)d_ws;
  prepack_kernel<<<24, 256, 0, stream>>>(
      (const float*)d_in[2], (const float*)d_in[3], (const float*)d_in[4], (const float*)d_in[5],
      (const float*)d_in[6], (const float*)d_in[7], (const float*)d_in[8], (const float*)d_in[9],
      (const float*)d_in[10], (const float*)d_in[11], (const float*)d_in[12], (const float*)d_in[13],
      (const float*)d_in[14], (const float*)d_in[15],
      (const float*)d_in[16], (const float*)d_in[17], (const float*)d_in[18], (const float*)d_in[19],
      (const float*)d_in[20], (const float*)d_in[21], (const float*)d_in[22], (const float*)d_in[23],
      (const float*)d_in[24], (const float*)d_in[25], (const float*)d_in[26], (const float*)d_in[27],
      (const float*)d_in[28], (const float*)d_in[29],
      (const float*)d_in[30], (const float*)d_in[31], (const float*)d_in[32], (const float*)d_in[33],
      (const float*)d_in[34], (const float*)d_in[35],
      ws);
  tf_kernel<<<32, 1024, 0, stream>>>((const float*)d_in[0], (const float*)d_in[1], ws,
                                     (float*)d_out);
}